// Round 16
// baseline (555.577 us; speedup 1.0000x reference)
//
#include <hip/hip_runtime.h>
#include <math.h>

typedef unsigned int   u32;
typedef unsigned short u16;
typedef unsigned long long u64;
typedef __attribute__((ext_vector_type(8))) short short8;
typedef __attribute__((ext_vector_type(4))) float f32x4;

#define TAUF 0.0350f
#define CAP  192
#define QB2  8
#define LSLOT 104

__device__ __forceinline__ u16 f2b(float f) {
  u32 u = __float_as_uint(f);
  u += 0x7fffu + ((u >> 16) & 1u);   // RNE
  return (u16)(u >> 16);
}

__device__ __forceinline__ void gload_lds16(const void* g, void* l) {
  __builtin_amdgcn_global_load_lds(
      (const __attribute__((address_space(1))) u32*)g,
      (__attribute__((address_space(3))) u32*)l, 16, 0, 0);
}

// monotone (v desc, idx asc) total order as unsigned-descending u64
__device__ __forceinline__ u64 packkey(float v, int idx) {
  u32 u = __float_as_uint(v);
  u32 mu = (u & 0x80000000u) ? ~u : (u | 0x80000000u);
  return ((u64)mu << 32) | (u32)(0xFFFF - idx);
}
__device__ __forceinline__ float unpack_v(u64 k) {
  u32 mu = (u32)(k >> 32);
  u32 u = (mu & 0x80000000u) ? (mu ^ 0x80000000u) : ~mu;
  return __uint_as_float(u);
}
__device__ __forceinline__ int unpack_i(u64 k) {
  return 0xFFFF - (int)(k & 0xFFFFu);
}

#define FMA16 \
  acc[0][0]=fmaf(a4.x,b4.x,acc[0][0]); acc[0][1]=fmaf(a4.x,b4.y,acc[0][1]); \
  acc[0][2]=fmaf(a4.x,b4.z,acc[0][2]); acc[0][3]=fmaf(a4.x,b4.w,acc[0][3]); \
  acc[1][0]=fmaf(a4.y,b4.x,acc[1][0]); acc[1][1]=fmaf(a4.y,b4.y,acc[1][1]); \
  acc[1][2]=fmaf(a4.y,b4.z,acc[1][2]); acc[1][3]=fmaf(a4.y,b4.w,acc[1][3]); \
  acc[2][0]=fmaf(a4.z,b4.x,acc[2][0]); acc[2][1]=fmaf(a4.z,b4.y,acc[2][1]); \
  acc[2][2]=fmaf(a4.z,b4.z,acc[2][2]); acc[2][3]=fmaf(a4.z,b4.w,acc[2][3]); \
  acc[3][0]=fmaf(a4.w,b4.x,acc[3][0]); acc[3][1]=fmaf(a4.w,b4.y,acc[3][1]); \
  acc[3][2]=fmaf(a4.w,b4.z,acc[3][2]); acc[3][3]=fmaf(a4.w,b4.w,acc[3][3]);

// ---------- QKV projection: fp32 C[2048,512] = A @ W[512,512] + b ----------
__global__ __launch_bounds__(256) void gemm_qkv(const float* __restrict__ x,
    const float* __restrict__ Wq, const float* __restrict__ bq,
    const float* __restrict__ Wk, const float* __restrict__ bk,
    const float* __restrict__ Wv, const float* __restrict__ bv,
    float* __restrict__ Qo, float* __restrict__ Ko, float* __restrict__ Vo)
{
  __shared__ float As[16][68];
  __shared__ float Bs[16][68];
  int z = blockIdx.z;
  const float* W    = (z == 0) ? Wq : (z == 1) ? Wk : Wv;
  const float* bias = (z == 0) ? bq : (z == 1) ? bk : bv;
  float*       out  = (z == 0) ? Qo : (z == 1) ? Ko : Vo;
  int t = threadIdx.x;
  int m0 = blockIdx.y * 64, n0 = blockIdx.x * 64;
  int tx = t & 15, ty = t >> 4;
  int am = t >> 2, ak = (t & 3) * 4;
  int bkk = t >> 4, bn = (t & 15) * 4;
  float acc[4][4] = {};
  for (int k0 = 0; k0 < 512; k0 += 16) {
    float4 fa = *(const float4*)&x[(m0 + am) * 512 + k0 + ak];
    float4 fb = *(const float4*)&W[(k0 + bkk) * 512 + n0 + bn];
    As[ak + 0][am] = fa.x; As[ak + 1][am] = fa.y;
    As[ak + 2][am] = fa.z; As[ak + 3][am] = fa.w;
    Bs[bkk][bn + 0] = fb.x; Bs[bkk][bn + 1] = fb.y;
    Bs[bkk][bn + 2] = fb.z; Bs[bkk][bn + 3] = fb.w;
    __syncthreads();
    #pragma unroll
    for (int kk = 0; kk < 16; ++kk) {
      float4 a4 = *(const float4*)&As[kk][ty * 4];
      float4 b4 = *(const float4*)&Bs[kk][tx * 4];
      FMA16
    }
    __syncthreads();
  }
  float bb0 = bias[n0+tx*4+0], bb1 = bias[n0+tx*4+1];
  float bb2 = bias[n0+tx*4+2], bb3 = bias[n0+tx*4+3];
  #pragma unroll
  for (int r = 0; r < 4; ++r) {
    float4 o = { acc[r][0] + bb0, acc[r][1] + bb1, acc[r][2] + bb2, acc[r][3] + bb3 };
    *(float4*)&out[(m0 + ty*4 + r) * 512 + n0 + tx*4] = o;
  }
}

// ---------- output projection fused with gate-combine:
// out = (g*WT + (1-g)*ATT) @ Wo + bo ----------
__global__ __launch_bounds__(256) void gemm_out_k(const float* __restrict__ ATT,
    const float* __restrict__ WT, const float* __restrict__ gate,
    const float* __restrict__ W, const float* __restrict__ bias, float* __restrict__ out)
{
  __shared__ float As[16][68];
  __shared__ float Bs[16][68];
  __shared__ float gl[8];
  int t = threadIdx.x;
  if (t < 8) gl[t] = 1.0f / (1.0f + __expf(-gate[t]));
  __syncthreads();
  int m0 = blockIdx.y * 64, n0 = blockIdx.x * 64;
  int tx = t & 15, ty = t >> 4;
  int am = t >> 2, ak = (t & 3) * 4;
  int bkk = t >> 4, bn = (t & 15) * 4;
  int r_g = m0 + am;                       // global row
  int bo = r_g >> 10, s = r_g & 1023;
  float acc[4][4] = {};
  for (int k0 = 0; k0 < 512; k0 += 16) {
    int c = k0 + ak;                       // global col in [0,512), c%4==0
    int ho = c >> 6, dk = c & 63;          // float4 never crosses ho boundary
    float4 av = *(const float4*)&ATT[(((ho * 2 + bo) << 10) + s) * 64 + dk];
    float4 wv = *(const float4*)&WT[((ho << 11) + r_g) * 64 + dk];
    float g = gl[ho];
    float4 fb = *(const float4*)&W[(k0 + bkk) * 512 + n0 + bn];
    As[ak + 0][am] = g * wv.x + (1.0f - g) * av.x;
    As[ak + 1][am] = g * wv.y + (1.0f - g) * av.y;
    As[ak + 2][am] = g * wv.z + (1.0f - g) * av.z;
    As[ak + 3][am] = g * wv.w + (1.0f - g) * av.w;
    Bs[bkk][bn + 0] = fb.x; Bs[bkk][bn + 1] = fb.y;
    Bs[bkk][bn + 2] = fb.z; Bs[bkk][bn + 3] = fb.w;
    __syncthreads();
    #pragma unroll
    for (int kk = 0; kk < 16; ++kk) {
      float4 a4 = *(const float4*)&As[kk][ty * 4];
      float4 b4 = *(const float4*)&Bs[kk][tx * 4];
      FMA16
    }
    __syncthreads();
  }
  float bb0 = bias[n0+tx*4+0], bb1 = bias[n0+tx*4+1];
  float bb2 = bias[n0+tx*4+2], bb3 = bias[n0+tx*4+3];
  #pragma unroll
  for (int r = 0; r < 4; ++r) {
    float4 o = { acc[r][0] + bb0, acc[r][1] + bb1, acc[r][2] + bb2, acc[r][3] + bb3 };
    *(float4*)&out[(m0 + ty*4 + r) * 512 + n0 + tx*4] = o;
  }
}

// ---------- memory-path q̂ in fp64: QM64/QM32 [16384][64], pre-scaled by 1/((||q||+1e-8)*8) ----------
// b128 LDS reads; per-acc[j] FMA chain order unchanged -> bit-identical
__global__ __launch_bounds__(256) void qmem64_kernel(const float* __restrict__ x,
    const float* __restrict__ Wq, const float* __restrict__ bq,
    double* __restrict__ QM64, float* __restrict__ QM32)
{
  __shared__ float xs[32][68];
  __shared__ float wsh[64][68];
  __shared__ double psum[32][8];
  __shared__ double scal[32];
  int t = threadIdx.x;
  int qq0 = blockIdx.x * 32;                  // 32 consecutive queries: same (b1,h1), s=s0..s0+31
  int b1 = qq0 >> 13, h1 = (qq0 >> 10) & 7, s0 = qq0 & 1023;
  int i = h1 * 2 + b1;                        // torch-reshape scramble
  int batch = i >> 3, col0 = (i & 7) * 64;
  int row = t >> 3, cg = (t & 7) * 8;
  double acc[8] = {};
  for (int k0 = 0; k0 < 512; k0 += 64) {
    #pragma unroll
    for (int j = 0; j < 2; ++j) {
      int idx = t + j * 256;
      int r = idx >> 4, c = (idx & 15) * 4;
      float4 f = *(const float4*)&x[(batch * 1024 + s0 + r) * 512 + k0 + c];
      xs[r][c+0] = f.x; xs[r][c+1] = f.y; xs[r][c+2] = f.z; xs[r][c+3] = f.w;
    }
    #pragma unroll
    for (int j = 0; j < 4; ++j) {
      int idx = t + j * 256;
      int r = idx >> 4, c = (idx & 15) * 4;
      float4 f = *(const float4*)&Wq[(k0 + r) * 512 + col0 + c];
      wsh[r][c+0] = f.x; wsh[r][c+1] = f.y; wsh[r][c+2] = f.z; wsh[r][c+3] = f.w;
    }
    __syncthreads();
    for (int kk = 0; kk < 64; kk += 4) {      // b128 reads; same kk/j order as scalar version
      float4 xv4 = *(const float4*)&xs[row][kk];
      #pragma unroll
      for (int s4 = 0; s4 < 4; ++s4) {
        float xf = (s4 == 0) ? xv4.x : (s4 == 1) ? xv4.y : (s4 == 2) ? xv4.z : xv4.w;
        double xv = (double)xf;
        float4 wa = *(const float4*)&wsh[kk + s4][cg];
        float4 wb = *(const float4*)&wsh[kk + s4][cg + 4];
        acc[0] = fma(xv, (double)wa.x, acc[0]);
        acc[1] = fma(xv, (double)wa.y, acc[1]);
        acc[2] = fma(xv, (double)wa.z, acc[2]);
        acc[3] = fma(xv, (double)wa.w, acc[3]);
        acc[4] = fma(xv, (double)wb.x, acc[4]);
        acc[5] = fma(xv, (double)wb.y, acc[5]);
        acc[6] = fma(xv, (double)wb.z, acc[6]);
        acc[7] = fma(xv, (double)wb.w, acc[7]);
      }
    }
    __syncthreads();
  }
  #pragma unroll
  for (int j = 0; j < 8; ++j) acc[j] += (double)bq[col0 + cg + j];
  double ps = 0.0;
  #pragma unroll
  for (int j = 0; j < 8; ++j) ps = fma(acc[j], acc[j], ps);
  psum[row][t & 7] = ps;
  __syncthreads();
  if (t < 32) {
    double s = 0.0;
    #pragma unroll
    for (int j = 0; j < 8; ++j) s += psum[t][j];
    scal[t] = 1.0 / ((sqrt(s) + 1e-8) * 8.0);
  }
  __syncthreads();
  double sc = scal[row];
  #pragma unroll
  for (int j = 0; j < 8; ++j) {
    double v = acc[j] * sc;
    QM64[(qq0 + row) * 64 + cg + j] = v;
    QM32[(qq0 + row) * 64 + cg + j] = (float)v;
  }
}

// ---------- fused per-memory prep: fp64 norm (kinv64, tau32) + bf16 convert (KB16) ----------
// one thread per memory row; reads Km once (was 2x across kprep+kcvt), outputs bit-identical
__global__ __launch_bounds__(256) void kprep_kernel(const float* __restrict__ Km,
    double* __restrict__ kinv64, float* __restrict__ tau32, u32* __restrict__ KB)
{
  int idx = blockIdx.x * 256 + threadIdx.x;   // 65536 rows
  const float* p = Km + idx * 64;
  float4 f[16];
  #pragma unroll
  for (int j = 0; j < 16; ++j) f[j] = *(const float4*)&p[j * 4];
  double s = 0.0;
  #pragma unroll
  for (int j = 0; j < 16; ++j) {
    double a = f[j].x, b = f[j].y, c = f[j].z, d = f[j].w;
    s = fma(a, a, s); s = fma(b, b, s); s = fma(c, c, s); s = fma(d, d, s);
  }
  double nrm = sqrt(s) + 1e-8;
  kinv64[idx] = 1.0 / nrm;
  tau32[idx] = (float)((double)TAUF * nrm);
  // bf16 row, same layout as the old kcvt kernel: KB[idx*32 .. +32) u32s
  u32* kb = KB + idx * 32;
  #pragma unroll
  for (int j = 0; j < 8; ++j) {                 // j-th pair of float4 -> uint4
    float4 f0 = f[2 * j], f1 = f[2 * j + 1];
    uint4 u;
    u.x = ((u32)f2b(f0.y) << 16) | f2b(f0.x);
    u.y = ((u32)f2b(f0.w) << 16) | f2b(f0.z);
    u.z = ((u32)f2b(f1.y) << 16) | f2b(f1.x);
    u.w = ((u32)f2b(f1.w) << 16) | f2b(f1.z);
    *(uint4*)&kb[j * 4] = u;
  }
}

// ---------- causal attention: 4 query rows per block, batch-head i = blockIdx.y ----------
// q row hoisted to 16 float4 VGPRs (kills per-chunk qs LDS reads); [68]-padded K tile,
// b128 score reads, float4 sl PV reads.  FMA chain order unchanged -> bit-identical output
__global__ __launch_bounds__(256) void attn_kernel(const float* __restrict__ Qb,
    const float* __restrict__ Kb, const float* __restrict__ Vb, float* __restrict__ attn)
{
  __shared__ float qs[4][64];
  __shared__ float Kc[64][68];
  __shared__ float sl[4][1024];
  int bi = blockIdx.y;               // i = borig*8 + horig
  int sq0 = blockIdx.x * 4;
  int borig = bi >> 3, horig = bi & 7;
  int t = threadIdx.x;
  int base = borig * 524288 + horig * 64;
  int w = t >> 6, l = t & 63;
  qs[w][l] = Qb[base + (sq0 + w) * 512 + l];
  __syncthreads();
  // hoist this wave's q row into registers (read once; was re-read every chunk)
  float4 fq[16];
  #pragma unroll
  for (int j = 0; j < 16; ++j) fq[j] = *(const float4*)&qs[w][j * 4];
  int nk = sq0 + 4;
  for (int k0 = 0; k0 < nk; k0 += 64) {
    #pragma unroll
    for (int j = 0; j < 4; ++j) {
      int idx = t + j * 256;
      int key = idx >> 4, f = idx & 15;
      if (k0 + key < nk) {
        float4 kv = *(const float4*)&Kb[base + (k0 + key) * 512 + f * 4];
        *(float4*)&Kc[key][f * 4] = kv;       // rows 16B-aligned (68*4 bytes)
      }
    }
    __syncthreads();
    int key = k0 + l;
    if (key <= sq0 + w) {
      float dv = 0.f;
      #pragma unroll
      for (int d = 0; d < 16; ++d) {          // b128 Kc reads; q from VGPRs
        float4 q4 = fq[d];
        float4 k4 = *(const float4*)&Kc[l][d * 4];
        dv = fmaf(q4.x, k4.x, dv);
        dv = fmaf(q4.y, k4.y, dv);
        dv = fmaf(q4.z, k4.z, dv);
        dv = fmaf(q4.w, k4.w, dv);
      }
      sl[w][key] = dv * 0.125f;
    }
    __syncthreads();
  }
  int nkr = sq0 + w + 1;
  float mx = -__builtin_inff();
  for (int k = l; k < nkr; k += 64) mx = fmaxf(mx, sl[w][k]);
  #pragma unroll
  for (int msk = 32; msk >= 1; msk >>= 1) mx = fmaxf(mx, __shfl_xor(mx, msk));
  float sum = 0.f;
  for (int k = l; k < nkr; k += 64) { float p = __expf(sl[w][k] - mx); sl[w][k] = p; sum += p; }
  #pragma unroll
  for (int msk = 32; msk >= 1; msk >>= 1) sum += __shfl_xor(sum, msk);
  float inv = 1.0f / sum;
  __syncthreads();
  // PV: float4 sl reads (4 keys per LDS instr), same FMA order as scalar loop -> bit-identical
  float acc = 0.f;
  const float* vp = &Vb[base + l];
  int k = 0;
  #pragma unroll 2
  for (; k + 4 <= nkr; k += 4) {
    float4 p4 = *(const float4*)&sl[w][k];    // 16B-aligned (row stride 4KB)
    acc = fmaf(p4.x, vp[(k + 0) * 512], acc);
    acc = fmaf(p4.y, vp[(k + 1) * 512], acc);
    acc = fmaf(p4.z, vp[(k + 2) * 512], acc);
    acc = fmaf(p4.w, vp[(k + 3) * 512], acc);
  }
  for (; k < nkr; ++k) acc = fmaf(sl[w][k], vp[k * 512], acc);
  attn[(bi * 1024 + sq0 + w) * 64 + l] = acc * inv;
}

// ---------- KNN filter v2: bf16 MFMA raw dots vs tau -> LDS candidate lists -> block flush ----
// Accepts go to per-query LDS lists (fast ds atomics); one global atomicAdd per query per block
// reserves the pidx span, then coalesced copy-out.  Overflow (>LSLOT local) falls back to the
// old direct-global path, so pcnt totals and the stored SET are exact.
__global__ __launch_bounds__(256) void knnA_kernel(
    const float* __restrict__ QM32, const u16* __restrict__ KB16,
    const float* __restrict__ tau32, u32* __restrict__ pcnt, u16* __restrict__ pidx)
{
  __shared__ u16   Kc[2][128 * 64];
  __shared__ float tauc[2][128];
  __shared__ u16   lidx[32][LSLOT];
  __shared__ u32   lcnt[32];
  __shared__ u32   gbase[32];
  int t = threadIdx.x;
  int l = t & 63, w = t >> 6;
  int lane15 = l & 15, quad = l >> 4;
  int bidx = blockIdx.x;
  int h2  = bidx & 7;                         // head -> XCD cluster
  int qq0 = (h2 << 11) | ((bidx >> 3) << 5);
  int mbase = blockIdx.y * 4096;              // shard
  const u16* KBh = KB16 + (size_t)(h2 * 8192) * 64;
  const float* tauh = tau32 + h2 * 8192;
  if (t < 32) lcnt[t] = 0;
  // A-frags: q̂ rows (bf16), resident in VGPRs
  short8 afr[2][2];
  #pragma unroll
  for (int qt = 0; qt < 2; ++qt) {
    int q = qq0 + qt * 16 + lane15;
    #pragma unroll
    for (int kh = 0; kh < 2; ++kh) {
      const float* qp = &QM32[q * 64 + kh * 32 + quad * 8];
      float4 fa = *(const float4*)qp;
      float4 fb = *(const float4*)(qp + 4);
      short8 a;
      a[0]=(short)f2b(fa.x); a[1]=(short)f2b(fa.y); a[2]=(short)f2b(fa.z); a[3]=(short)f2b(fa.w);
      a[4]=(short)f2b(fb.x); a[5]=(short)f2b(fb.y); a[6]=(short)f2b(fb.z); a[7]=(short)f2b(fb.w);
      afr[qt][kh] = a;
    }
  }
  // --- staging helper (async): chunk c of this shard into buffer buf ---
  #define STAGE(buf, c) do { \
    int m0s = mbase + (c) * 128; \
    _Pragma("unroll") \
    for (int i2 = 0; i2 < 4; ++i2) { \
      int slot = i2 * 256 + t; \
      int mm = slot >> 3, gs = slot & 7; \
      int gsrc = gs ^ (mm & 7); \
      gload_lds16(KBh + (size_t)(m0s + mm) * 64 + gsrc * 8, \
                  &Kc[buf][(size_t)(i2 * 256 + (t & ~63)) * 8]); \
    } \
    if (t < 32) gload_lds16(&tauh[m0s + t * 4], &tauc[buf][0]); \
  } while (0)

  STAGE(0, 0);
  __syncthreads();
  for (int c = 0; c < 32; ++c) {
    int cur = c & 1;
    if (c + 1 < 32) STAGE(cur ^ 1, c + 1);
    #pragma unroll
    for (int mi = 0; mi < 2; ++mi) {
      int mt = 2 * w + mi;
      int m = mt * 16 + lane15;
      float tau_m = tauc[cur][m];
      short8 b0 = *(const short8*)&Kc[cur][(m * 8 + (quad       ^ (m & 7))) * 8];
      short8 b1 = *(const short8*)&Kc[cur][(m * 8 + ((4 + quad) ^ (m & 7))) * 8];
      int m_g = mbase + c * 128 + m;
      #pragma unroll
      for (int qt = 0; qt < 2; ++qt) {
        f32x4 z = {0.f, 0.f, 0.f, 0.f};
        z = __builtin_amdgcn_mfma_f32_16x16x32_bf16(afr[qt][0], b0, z, 0, 0, 0);
        z = __builtin_amdgcn_mfma_f32_16x16x32_bf16(afr[qt][1], b1, z, 0, 0, 0);
        #pragma unroll
        for (int r4 = 0; r4 < 4; ++r4) {
          if (z[r4] > tau_m) {                       // raw dot vs TAU*||K_m||
            int qloc = qt * 16 + quad * 4 + r4;      // block-local query (0..31)
            u32 p = atomicAdd(&lcnt[qloc], 1u);      // fast LDS atomic
            if (p < LSLOT) {
              lidx[qloc][p] = (u16)m_g;
            } else {                                 // rare overflow: direct global
              int ql = qq0 + qloc;
              u32 gp = atomicAdd(&pcnt[ql], 1u);
              if (gp < CAP) pidx[(size_t)ql * CAP + gp] = (u16)m_g;
            }
          }
        }
      }
    }
    __syncthreads();
  }
  #undef STAGE
  // --- flush: reserve span per query (1 global atomic each), coalesced copy-out ---
  if (t < 32) {
    u32 cnt = min(lcnt[t], (u32)LSLOT);
    gbase[t] = atomicAdd(&pcnt[qq0 + t], cnt);
  }
  __syncthreads();
  for (int q = 0; q < 32; ++q) {
    u32 cnt = min(lcnt[q], (u32)LSLOT);
    u32 gb = gbase[q];
    for (u32 s = t; s < cnt; s += 256) {
      u32 p = gb + s;
      if (p < CAP) pidx[(size_t)(qq0 + q) * CAP + p] = lidx[q][s];
    }
  }
}

// ---------- KNN select v4: 8-lane coalesced fp64 rescore (3-shfl butterfly) ----------
// -> HALF-WAVE u64-key top-33 (lanes 0-31: qA, 32-63: qB; 5 shfl steps, 1 query each)
// -> soft-blend -> fp64 V-sum.  No __syncthreads (wave-local LDS rows).
__global__ __launch_bounds__(256) void knnB_kernel(
    const u32* __restrict__ pcnt, const u16* __restrict__ pidx,
    const double* __restrict__ QM64, const float* __restrict__ Km,
    const float* __restrict__ Vm, const double* __restrict__ kinv64,
    float* __restrict__ wt)
{
  __shared__ float pool_v[QB2][CAP];
  __shared__ u16   pool_i[QB2][CAP];
  __shared__ float out_v[QB2][34];
  __shared__ u16   out_i[QB2][34];
  int t = threadIdx.x;
  int bid = blockIdx.x;
  int h2  = bid & 7;
  int qq0 = (h2 << 11) | ((bid >> 3) << 3);
  int w = t >> 6, l = t & 63;
  int qA = 2 * w, qB = 2 * w + 1;                 // this wave's two queries (block-local)
  int gA = qq0 + qA, gB = qq0 + qB;
  int n0 = min((int)pcnt[gA], CAP);               // broadcast loads, wave-uniform
  int n1 = min((int)pcnt[gB], CAP);
  int c8 = l & 7, grp8 = l >> 3;                  // 8-lane groups, 8 slots/pass
  const float*  Kmh   = Km + (size_t)h2 * 524288;
  const double* kinvh = kinv64 + h2 * 8192;
  // --- rescore query A: 24 passes x 8 slots; per-group reads 2x128B contiguous ---
  {
    double2 q0 = *(const double2*)&QM64[gA * 64 + c8 * 4];
    double2 q1 = *(const double2*)&QM64[gA * 64 + c8 * 4 + 2];
    double2 q2 = *(const double2*)&QM64[gA * 64 + 32 + c8 * 4];
    double2 q3 = *(const double2*)&QM64[gA * 64 + 32 + c8 * 4 + 2];
    #pragma unroll 8
    for (int p = 0; p < 24; ++p) {
      int j = p * 8 + grp8;
      bool val = j < n0;
      int id = val ? (int)pidx[(size_t)gA * CAP + j] : 0;
      float4 k0 = *(const float4*)&Kmh[id * 64 + c8 * 4];
      float4 k1 = *(const float4*)&Kmh[id * 64 + 32 + c8 * 4];
      double pl = q0.x * (double)k0.x;
      pl = fma(q0.y, (double)k0.y, pl);
      pl = fma(q1.x, (double)k0.z, pl);
      pl = fma(q1.y, (double)k0.w, pl);
      pl = fma(q2.x, (double)k1.x, pl);
      pl = fma(q2.y, (double)k1.y, pl);
      pl = fma(q3.x, (double)k1.z, pl);
      pl = fma(q3.y, (double)k1.w, pl);
      pl += __shfl_xor(pl, 1);
      pl += __shfl_xor(pl, 2);
      pl += __shfl_xor(pl, 4);
      if (c8 == 0) {
        pool_v[qA][j] = val ? (float)(pl * kinvh[id]) : -1e30f;
        pool_i[qA][j] = (u16)id;
      }
    }
  }
  // --- rescore query B ---
  {
    double2 q0 = *(const double2*)&QM64[gB * 64 + c8 * 4];
    double2 q1 = *(const double2*)&QM64[gB * 64 + c8 * 4 + 2];
    double2 q2 = *(const double2*)&QM64[gB * 64 + 32 + c8 * 4];
    double2 q3 = *(const double2*)&QM64[gB * 64 + 32 + c8 * 4 + 2];
    #pragma unroll 8
    for (int p = 0; p < 24; ++p) {
      int j = p * 8 + grp8;
      bool val = j < n1;
      int id = val ? (int)pidx[(size_t)gB * CAP + j] : 0;
      float4 k0 = *(const float4*)&Kmh[id * 64 + c8 * 4];
      float4 k1 = *(const float4*)&Kmh[id * 64 + 32 + c8 * 4];
      double pl = q0.x * (double)k0.x;
      pl = fma(q0.y, (double)k0.y, pl);
      pl = fma(q1.x, (double)k0.z, pl);
      pl = fma(q1.y, (double)k0.w, pl);
      pl = fma(q2.x, (double)k1.x, pl);
      pl = fma(q2.y, (double)k1.y, pl);
      pl = fma(q3.x, (double)k1.z, pl);
      pl = fma(q3.y, (double)k1.w, pl);
      pl += __shfl_xor(pl, 1);
      pl += __shfl_xor(pl, 2);
      pl += __shfl_xor(pl, 4);
      if (c8 == 0) {
        pool_v[qB][j] = val ? (float)(pl * kinvh[id]) : -1e30f;
        pool_i[qB][j] = (u16)id;
      }
    }
  }
  // no barrier: pool rows 2w,2w+1 written and read by this wave only (same-wave DS ordering)
  // --- half-wave selection: lanes 0-31 own qA, lanes 32-63 own qB; 6 keys/lane ---
  int half = l >> 5, hl = l & 31;
  int qS = 2 * w + half;                          // block-local query for this half
  u64 k0 = packkey(pool_v[qS][hl],       (int)pool_i[qS][hl]);
  u64 k1 = packkey(pool_v[qS][hl + 32],  (int)pool_i[qS][hl + 32]);
  u64 k2 = packkey(pool_v[qS][hl + 64],  (int)pool_i[qS][hl + 64]);
  u64 k3 = packkey(pool_v[qS][hl + 96],  (int)pool_i[qS][hl + 96]);
  u64 k4 = packkey(pool_v[qS][hl + 128], (int)pool_i[qS][hl + 128]);
  u64 k5 = packkey(pool_v[qS][hl + 160], (int)pool_i[qS][hl + 160]);
  for (int r = 0; r < 33; ++r) {
    u64 b = k0; int bs = 0;
    if (k1 > b) { b = k1; bs = 1; }
    if (k2 > b) { b = k2; bs = 2; }
    if (k3 > b) { b = k3; bs = 3; }
    if (k4 > b) { b = k4; bs = 4; }
    if (k5 > b) { b = k5; bs = 5; }
    u64 rk = b;
    #pragma unroll
    for (int m = 16; m >= 1; m >>= 1) {           // masks <=16 never cross halves
      u64 o = __shfl_xor(rk, m);
      if (o > rk) rk = o;
    }
    if (b == rk) {                                 // unique keys -> one lane clears
      if (bs == 0) k0 = 0ULL; else if (bs == 1) k1 = 0ULL; else if (bs == 2) k2 = 0ULL;
      else if (bs == 3) k3 = 0ULL; else if (bs == 4) k4 = 0ULL; else k5 = 0ULL;
    }
    if (hl == 0) {
      out_v[qS][r] = unpack_v(rk); out_i[qS][r] = (u16)unpack_i(rk);
    }
  }
  if (hl == 0) {   // soft-blend rank 32/33 boundary (lane 0 -> qA, lane 32 -> qB)
    float gx = out_v[qS][31] - out_v[qS][32];
    float lam = 0.5f * erfcf(gx * 471404.52f);    // 1/(sqrt(2)*1.5e-6)
    out_v[qS][31] *= (1.0f - lam);
    out_v[qS][32] *= lam;
  }
  // fp64 V-sum, both queries interleaved; deep unroll so gather loads issue ahead
  const float* Vmh = Vm + (size_t)h2 * 524288;
  double accA = 0.0, accB = 0.0;
  #pragma unroll 11
  for (int j = 0; j < 33; ++j) {
    float vA = out_v[qA][j]; int idA = out_i[qA][j];
    float vB = out_v[qB][j]; int idB = out_i[qB][j];
    if (vA > -1e29f) accA = fma((double)vA, (double)Vmh[idA * 64 + l], accA);
    if (vB > -1e29f) accB = fma((double)vB, (double)Vmh[idB * 64 + l], accB);
  }
  wt[gA * 64 + l] = (float)accA;
  wt[gB * 64 + l] = (float)accB;
}

extern "C" void kernel_launch(void* const* d_in, const int* in_sizes, int n_in,
                              void* d_out, int out_size, void* d_ws, size_t ws_size,
                              hipStream_t stream) {
  const float* x    = (const float*)d_in[0];
  const float* Wq   = (const float*)d_in[1];
  const float* bq   = (const float*)d_in[2];
  const float* Wk   = (const float*)d_in[3];
  const float* bk   = (const float*)d_in[4];
  const float* Wv   = (const float*)d_in[5];
  const float* bv   = (const float*)d_in[6];
  const float* Wo   = (const float*)d_in[7];
  const float* bo   = (const float*)d_in[8];
  const float* Km   = (const float*)d_in[9];
  const float* Vm   = (const float*)d_in[10];
  const float* gate = (const float*)d_in[11];
  float* out = (float*)d_out;
  float* ws = (float*)d_ws;
  // layout (floats). KB16 overlays WT region before knnB writes it; pool overlays Q/K.
  float*  Q      = ws;                         // [0, 1048576)
  float*  K      = ws + 1048576;               // [1048576, 2097152)
  float*  V      = ws + 2097152;               // [2097152, 3145728)
  float*  ATT    = ws + 3145728;               // [3145728, 4194304)
  float*  WT     = ws + 4194304;               // [4194304, 5242880)  (written by knnB)
  u16*    KB16   = (u16*)(ws + 4194304);       // 8.39 MB, lifetime kprep..knnA (before WT write)
  float*  QM32   = ws + 6291456;               // 1048576
  float*  TAU32  = ws + 7340032;               // 65536
  double* QM64   = (double*)(ws + 7405568);    // 1048576 doubles
  double* KINV64 = (double*)(ws + 9502720);    // 65536 doubles
  u32*    PCNT   = (u32*)ws;                   // 16384 u32, lifetime post-attn (over Q)
  u16*    PIDX   = (u16*)(ws + 16384);         // 16384*CAP u16 (over Q/K)
  gemm_qkv<<<dim3(8, 32, 3), 256, 0, stream>>>(x, Wq, bq, Wk, bk, Wv, bv, Q, K, V);
  qmem64_kernel<<<dim3(512), 256, 0, stream>>>(x, Wq, bq, QM64, QM32);
  kprep_kernel<<<dim3(256), 256, 0, stream>>>(Km, KINV64, TAU32, (u32*)KB16);
  attn_kernel<<<dim3(256, 16), 256, 0, stream>>>(Q, K, V, ATT);
  hipMemsetAsync(PCNT, 0, 16384 * sizeof(u32), stream);
  knnA_kernel<<<dim3(512, 2), 256, 0, stream>>>(QM32, KB16, TAU32, PCNT, PIDX);
  knnB_kernel<<<dim3(2048), 256, 0, stream>>>(PCNT, PIDX, QM64, Km, Vm, KINV64, WT);
  gemm_out_k<<<dim3(8, 32), 256, 0, stream>>>(ATT, WT, gate, Wo, bo, out);
}

// Round 17
// 552.321 us; speedup vs baseline: 1.0059x; 1.0059x over previous
//
#include <hip/hip_runtime.h>
#include <math.h>

typedef unsigned int   u32;
typedef unsigned short u16;
typedef unsigned long long u64;
typedef __attribute__((ext_vector_type(8))) short short8;
typedef __attribute__((ext_vector_type(4))) float f32x4;

#define TAUF 0.0350f
#define CAP  192
#define QB2  8
#define LSLOT 104

__device__ __forceinline__ u16 f2b(float f) {
  u32 u = __float_as_uint(f);
  u += 0x7fffu + ((u >> 16) & 1u);   // RNE
  return (u16)(u >> 16);
}

__device__ __forceinline__ void gload_lds16(const void* g, void* l) {
  __builtin_amdgcn_global_load_lds(
      (const __attribute__((address_space(1))) u32*)g,
      (__attribute__((address_space(3))) u32*)l, 16, 0, 0);
}

// monotone (v desc, idx asc) total order as unsigned-descending u64
__device__ __forceinline__ u64 packkey(float v, int idx) {
  u32 u = __float_as_uint(v);
  u32 mu = (u & 0x80000000u) ? ~u : (u | 0x80000000u);
  return ((u64)mu << 32) | (u32)(0xFFFF - idx);
}
__device__ __forceinline__ float unpack_v(u64 k) {
  u32 mu = (u32)(k >> 32);
  u32 u = (mu & 0x80000000u) ? (mu ^ 0x80000000u) : ~mu;
  return __uint_as_float(u);
}
__device__ __forceinline__ int unpack_i(u64 k) {
  return 0xFFFF - (int)(k & 0xFFFFu);
}

#define FMA16 \
  acc[0][0]=fmaf(a4.x,b4.x,acc[0][0]); acc[0][1]=fmaf(a4.x,b4.y,acc[0][1]); \
  acc[0][2]=fmaf(a4.x,b4.z,acc[0][2]); acc[0][3]=fmaf(a4.x,b4.w,acc[0][3]); \
  acc[1][0]=fmaf(a4.y,b4.x,acc[1][0]); acc[1][1]=fmaf(a4.y,b4.y,acc[1][1]); \
  acc[1][2]=fmaf(a4.y,b4.z,acc[1][2]); acc[1][3]=fmaf(a4.y,b4.w,acc[1][3]); \
  acc[2][0]=fmaf(a4.z,b4.x,acc[2][0]); acc[2][1]=fmaf(a4.z,b4.y,acc[2][1]); \
  acc[2][2]=fmaf(a4.z,b4.z,acc[2][2]); acc[2][3]=fmaf(a4.z,b4.w,acc[2][3]); \
  acc[3][0]=fmaf(a4.w,b4.x,acc[3][0]); acc[3][1]=fmaf(a4.w,b4.y,acc[3][1]); \
  acc[3][2]=fmaf(a4.w,b4.z,acc[3][2]); acc[3][3]=fmaf(a4.w,b4.w,acc[3][3]);

// ---------- QKV projection: fp32 C[2048,512] = A @ W[512,512] + b ----------
__global__ __launch_bounds__(256) void gemm_qkv(const float* __restrict__ x,
    const float* __restrict__ Wq, const float* __restrict__ bq,
    const float* __restrict__ Wk, const float* __restrict__ bk,
    const float* __restrict__ Wv, const float* __restrict__ bv,
    float* __restrict__ Qo, float* __restrict__ Ko, float* __restrict__ Vo)
{
  __shared__ float As[16][68];
  __shared__ float Bs[16][68];
  int z = blockIdx.z;
  const float* W    = (z == 0) ? Wq : (z == 1) ? Wk : Wv;
  const float* bias = (z == 0) ? bq : (z == 1) ? bk : bv;
  float*       out  = (z == 0) ? Qo : (z == 1) ? Ko : Vo;
  int t = threadIdx.x;
  int m0 = blockIdx.y * 64, n0 = blockIdx.x * 64;
  int tx = t & 15, ty = t >> 4;
  int am = t >> 2, ak = (t & 3) * 4;
  int bkk = t >> 4, bn = (t & 15) * 4;
  float acc[4][4] = {};
  for (int k0 = 0; k0 < 512; k0 += 16) {
    float4 fa = *(const float4*)&x[(m0 + am) * 512 + k0 + ak];
    float4 fb = *(const float4*)&W[(k0 + bkk) * 512 + n0 + bn];
    As[ak + 0][am] = fa.x; As[ak + 1][am] = fa.y;
    As[ak + 2][am] = fa.z; As[ak + 3][am] = fa.w;
    Bs[bkk][bn + 0] = fb.x; Bs[bkk][bn + 1] = fb.y;
    Bs[bkk][bn + 2] = fb.z; Bs[bkk][bn + 3] = fb.w;
    __syncthreads();
    #pragma unroll
    for (int kk = 0; kk < 16; ++kk) {
      float4 a4 = *(const float4*)&As[kk][ty * 4];
      float4 b4 = *(const float4*)&Bs[kk][tx * 4];
      FMA16
    }
    __syncthreads();
  }
  float bb0 = bias[n0+tx*4+0], bb1 = bias[n0+tx*4+1];
  float bb2 = bias[n0+tx*4+2], bb3 = bias[n0+tx*4+3];
  #pragma unroll
  for (int r = 0; r < 4; ++r) {
    float4 o = { acc[r][0] + bb0, acc[r][1] + bb1, acc[r][2] + bb2, acc[r][3] + bb3 };
    *(float4*)&out[(m0 + ty*4 + r) * 512 + n0 + tx*4] = o;
  }
}

// ---------- output projection fused with gate-combine:
// out = (g*WT + (1-g)*ATT) @ Wo + bo ----------
__global__ __launch_bounds__(256) void gemm_out_k(const float* __restrict__ ATT,
    const float* __restrict__ WT, const float* __restrict__ gate,
    const float* __restrict__ W, const float* __restrict__ bias, float* __restrict__ out)
{
  __shared__ float As[16][68];
  __shared__ float Bs[16][68];
  __shared__ float gl[8];
  int t = threadIdx.x;
  if (t < 8) gl[t] = 1.0f / (1.0f + __expf(-gate[t]));
  __syncthreads();
  int m0 = blockIdx.y * 64, n0 = blockIdx.x * 64;
  int tx = t & 15, ty = t >> 4;
  int am = t >> 2, ak = (t & 3) * 4;
  int bkk = t >> 4, bn = (t & 15) * 4;
  int r_g = m0 + am;                       // global row
  int bo = r_g >> 10, s = r_g & 1023;
  float acc[4][4] = {};
  for (int k0 = 0; k0 < 512; k0 += 16) {
    int c = k0 + ak;                       // global col in [0,512), c%4==0
    int ho = c >> 6, dk = c & 63;          // float4 never crosses ho boundary
    float4 av = *(const float4*)&ATT[(((ho * 2 + bo) << 10) + s) * 64 + dk];
    float4 wv = *(const float4*)&WT[((ho << 11) + r_g) * 64 + dk];
    float g = gl[ho];
    float4 fb = *(const float4*)&W[(k0 + bkk) * 512 + n0 + bn];
    As[ak + 0][am] = g * wv.x + (1.0f - g) * av.x;
    As[ak + 1][am] = g * wv.y + (1.0f - g) * av.y;
    As[ak + 2][am] = g * wv.z + (1.0f - g) * av.z;
    As[ak + 3][am] = g * wv.w + (1.0f - g) * av.w;
    Bs[bkk][bn + 0] = fb.x; Bs[bkk][bn + 1] = fb.y;
    Bs[bkk][bn + 2] = fb.z; Bs[bkk][bn + 3] = fb.w;
    __syncthreads();
    #pragma unroll
    for (int kk = 0; kk < 16; ++kk) {
      float4 a4 = *(const float4*)&As[kk][ty * 4];
      float4 b4 = *(const float4*)&Bs[kk][tx * 4];
      FMA16
    }
    __syncthreads();
  }
  float bb0 = bias[n0+tx*4+0], bb1 = bias[n0+tx*4+1];
  float bb2 = bias[n0+tx*4+2], bb3 = bias[n0+tx*4+3];
  #pragma unroll
  for (int r = 0; r < 4; ++r) {
    float4 o = { acc[r][0] + bb0, acc[r][1] + bb1, acc[r][2] + bb2, acc[r][3] + bb3 };
    *(float4*)&out[(m0 + ty*4 + r) * 512 + n0 + tx*4] = o;
  }
}

// ---------- memory-path q̂ in fp64: QM64/QM32 [16384][64], pre-scaled by 1/((||q||+1e-8)*8) ----------
// b128 LDS reads; per-acc[j] FMA chain order unchanged -> bit-identical
__global__ __launch_bounds__(256) void qmem64_kernel(const float* __restrict__ x,
    const float* __restrict__ Wq, const float* __restrict__ bq,
    double* __restrict__ QM64, float* __restrict__ QM32)
{
  __shared__ float xs[32][68];
  __shared__ float wsh[64][68];
  __shared__ double psum[32][8];
  __shared__ double scal[32];
  int t = threadIdx.x;
  int qq0 = blockIdx.x * 32;                  // 32 consecutive queries: same (b1,h1), s=s0..s0+31
  int b1 = qq0 >> 13, h1 = (qq0 >> 10) & 7, s0 = qq0 & 1023;
  int i = h1 * 2 + b1;                        // torch-reshape scramble
  int batch = i >> 3, col0 = (i & 7) * 64;
  int row = t >> 3, cg = (t & 7) * 8;
  double acc[8] = {};
  for (int k0 = 0; k0 < 512; k0 += 64) {
    #pragma unroll
    for (int j = 0; j < 2; ++j) {
      int idx = t + j * 256;
      int r = idx >> 4, c = (idx & 15) * 4;
      float4 f = *(const float4*)&x[(batch * 1024 + s0 + r) * 512 + k0 + c];
      xs[r][c+0] = f.x; xs[r][c+1] = f.y; xs[r][c+2] = f.z; xs[r][c+3] = f.w;
    }
    #pragma unroll
    for (int j = 0; j < 4; ++j) {
      int idx = t + j * 256;
      int r = idx >> 4, c = (idx & 15) * 4;
      float4 f = *(const float4*)&Wq[(k0 + r) * 512 + col0 + c];
      wsh[r][c+0] = f.x; wsh[r][c+1] = f.y; wsh[r][c+2] = f.z; wsh[r][c+3] = f.w;
    }
    __syncthreads();
    for (int kk = 0; kk < 64; kk += 4) {      // b128 reads; same kk/j order as scalar version
      float4 xv4 = *(const float4*)&xs[row][kk];
      #pragma unroll
      for (int s4 = 0; s4 < 4; ++s4) {
        float xf = (s4 == 0) ? xv4.x : (s4 == 1) ? xv4.y : (s4 == 2) ? xv4.z : xv4.w;
        double xv = (double)xf;
        float4 wa = *(const float4*)&wsh[kk + s4][cg];
        float4 wb = *(const float4*)&wsh[kk + s4][cg + 4];
        acc[0] = fma(xv, (double)wa.x, acc[0]);
        acc[1] = fma(xv, (double)wa.y, acc[1]);
        acc[2] = fma(xv, (double)wa.z, acc[2]);
        acc[3] = fma(xv, (double)wa.w, acc[3]);
        acc[4] = fma(xv, (double)wb.x, acc[4]);
        acc[5] = fma(xv, (double)wb.y, acc[5]);
        acc[6] = fma(xv, (double)wb.z, acc[6]);
        acc[7] = fma(xv, (double)wb.w, acc[7]);
      }
    }
    __syncthreads();
  }
  #pragma unroll
  for (int j = 0; j < 8; ++j) acc[j] += (double)bq[col0 + cg + j];
  double ps = 0.0;
  #pragma unroll
  for (int j = 0; j < 8; ++j) ps = fma(acc[j], acc[j], ps);
  psum[row][t & 7] = ps;
  __syncthreads();
  if (t < 32) {
    double s = 0.0;
    #pragma unroll
    for (int j = 0; j < 8; ++j) s += psum[t][j];
    scal[t] = 1.0 / ((sqrt(s) + 1e-8) * 8.0);
  }
  __syncthreads();
  double sc = scal[row];
  #pragma unroll
  for (int j = 0; j < 8; ++j) {
    double v = acc[j] * sc;
    QM64[(qq0 + row) * 64 + cg + j] = v;
    QM32[(qq0 + row) * 64 + cg + j] = (float)v;
  }
}

// ---------- fused per-memory prep: fp64 norm (kinv64, tau32) + bf16 convert (KB16) ----------
// one thread per memory row; reads Km once (was 2x across kprep+kcvt), outputs bit-identical
__global__ __launch_bounds__(256) void kprep_kernel(const float* __restrict__ Km,
    double* __restrict__ kinv64, float* __restrict__ tau32, u32* __restrict__ KB)
{
  int idx = blockIdx.x * 256 + threadIdx.x;   // 65536 rows
  const float* p = Km + idx * 64;
  float4 f[16];
  #pragma unroll
  for (int j = 0; j < 16; ++j) f[j] = *(const float4*)&p[j * 4];
  double s = 0.0;
  #pragma unroll
  for (int j = 0; j < 16; ++j) {
    double a = f[j].x, b = f[j].y, c = f[j].z, d = f[j].w;
    s = fma(a, a, s); s = fma(b, b, s); s = fma(c, c, s); s = fma(d, d, s);
  }
  double nrm = sqrt(s) + 1e-8;
  kinv64[idx] = 1.0 / nrm;
  tau32[idx] = (float)((double)TAUF * nrm);
  // bf16 row, same layout as the old kcvt kernel: KB[idx*32 .. +32) u32s
  u32* kb = KB + idx * 32;
  #pragma unroll
  for (int j = 0; j < 8; ++j) {                 // j-th pair of float4 -> uint4
    float4 f0 = f[2 * j], f1 = f[2 * j + 1];
    uint4 u;
    u.x = ((u32)f2b(f0.y) << 16) | f2b(f0.x);
    u.y = ((u32)f2b(f0.w) << 16) | f2b(f0.z);
    u.z = ((u32)f2b(f1.y) << 16) | f2b(f1.x);
    u.w = ((u32)f2b(f1.w) << 16) | f2b(f1.z);
    *(uint4*)&kb[j * 4] = u;
  }
}

// ---------- causal attention v3: 8 query rows per block (512 thr), batch-head i = blockIdx.y ----
// Same per-(row,lane) FMA chains as v2 -> bit-identical output.  Halves block count: K staging
// amortized over 8 rows, barrier count halved; LDS 51.4KB -> 3 blocks/CU = 24 waves (was 16).
__global__ __launch_bounds__(512) void attn_kernel(const float* __restrict__ Qb,
    const float* __restrict__ Kb, const float* __restrict__ Vb, float* __restrict__ attn)
{
  __shared__ float qs[8][64];
  __shared__ float Kc[64][68];
  __shared__ float sl[8][1024];
  int bi = blockIdx.y;               // i = borig*8 + horig
  int sq0 = blockIdx.x * 8;
  int borig = bi >> 3, horig = bi & 7;
  int t = threadIdx.x;
  int base = borig * 524288 + horig * 64;
  int w = t >> 6, l = t & 63;
  qs[w][l] = Qb[base + (sq0 + w) * 512 + l];
  __syncthreads();
  // hoist this wave's q row into registers
  float4 fq[16];
  #pragma unroll
  for (int j = 0; j < 16; ++j) fq[j] = *(const float4*)&qs[w][j * 4];
  int nk = sq0 + 8;
  for (int k0 = 0; k0 < nk; k0 += 64) {
    #pragma unroll
    for (int j = 0; j < 2; ++j) {
      int idx = t + j * 512;                  // 1024 float4 tasks over 512 threads
      int key = idx >> 4, f = idx & 15;
      if (k0 + key < nk) {
        float4 kv = *(const float4*)&Kb[base + (k0 + key) * 512 + f * 4];
        *(float4*)&Kc[key][f * 4] = kv;       // rows 16B-aligned (68*4 bytes)
      }
    }
    __syncthreads();
    int key = k0 + l;
    if (key <= sq0 + w) {
      float dv = 0.f;
      #pragma unroll
      for (int d = 0; d < 16; ++d) {          // b128 Kc reads; q from VGPRs
        float4 q4 = fq[d];
        float4 k4 = *(const float4*)&Kc[l][d * 4];
        dv = fmaf(q4.x, k4.x, dv);
        dv = fmaf(q4.y, k4.y, dv);
        dv = fmaf(q4.z, k4.z, dv);
        dv = fmaf(q4.w, k4.w, dv);
      }
      sl[w][key] = dv * 0.125f;
    }
    __syncthreads();
  }
  int nkr = sq0 + w + 1;
  float mx = -__builtin_inff();
  for (int k = l; k < nkr; k += 64) mx = fmaxf(mx, sl[w][k]);
  #pragma unroll
  for (int msk = 32; msk >= 1; msk >>= 1) mx = fmaxf(mx, __shfl_xor(mx, msk));
  float sum = 0.f;
  for (int k = l; k < nkr; k += 64) { float p = __expf(sl[w][k] - mx); sl[w][k] = p; sum += p; }
  #pragma unroll
  for (int msk = 32; msk >= 1; msk >>= 1) sum += __shfl_xor(sum, msk);
  float inv = 1.0f / sum;
  __syncthreads();
  // PV: float4 sl reads (4 keys per LDS instr), same FMA order as scalar loop -> bit-identical
  float acc = 0.f;
  const float* vp = &Vb[base + l];
  int k = 0;
  #pragma unroll 2
  for (; k + 4 <= nkr; k += 4) {
    float4 p4 = *(const float4*)&sl[w][k];    // 16B-aligned (row stride 4KB)
    acc = fmaf(p4.x, vp[(k + 0) * 512], acc);
    acc = fmaf(p4.y, vp[(k + 1) * 512], acc);
    acc = fmaf(p4.z, vp[(k + 2) * 512], acc);
    acc = fmaf(p4.w, vp[(k + 3) * 512], acc);
  }
  for (; k < nkr; ++k) acc = fmaf(sl[w][k], vp[k * 512], acc);
  attn[(bi * 1024 + sq0 + w) * 64 + l] = acc * inv;
}

// ---------- KNN filter v2: bf16 MFMA raw dots vs tau -> LDS candidate lists -> block flush ----
__global__ __launch_bounds__(256) void knnA_kernel(
    const float* __restrict__ QM32, const u16* __restrict__ KB16,
    const float* __restrict__ tau32, u32* __restrict__ pcnt, u16* __restrict__ pidx)
{
  __shared__ u16   Kc[2][128 * 64];
  __shared__ float tauc[2][128];
  __shared__ u16   lidx[32][LSLOT];
  __shared__ u32   lcnt[32];
  __shared__ u32   gbase[32];
  int t = threadIdx.x;
  int l = t & 63, w = t >> 6;
  int lane15 = l & 15, quad = l >> 4;
  int bidx = blockIdx.x;
  int h2  = bidx & 7;                         // head -> XCD cluster
  int qq0 = (h2 << 11) | ((bidx >> 3) << 5);
  int mbase = blockIdx.y * 4096;              // shard
  const u16* KBh = KB16 + (size_t)(h2 * 8192) * 64;
  const float* tauh = tau32 + h2 * 8192;
  if (t < 32) lcnt[t] = 0;
  // A-frags: q̂ rows (bf16), resident in VGPRs
  short8 afr[2][2];
  #pragma unroll
  for (int qt = 0; qt < 2; ++qt) {
    int q = qq0 + qt * 16 + lane15;
    #pragma unroll
    for (int kh = 0; kh < 2; ++kh) {
      const float* qp = &QM32[q * 64 + kh * 32 + quad * 8];
      float4 fa = *(const float4*)qp;
      float4 fb = *(const float4*)(qp + 4);
      short8 a;
      a[0]=(short)f2b(fa.x); a[1]=(short)f2b(fa.y); a[2]=(short)f2b(fa.z); a[3]=(short)f2b(fa.w);
      a[4]=(short)f2b(fb.x); a[5]=(short)f2b(fb.y); a[6]=(short)f2b(fb.z); a[7]=(short)f2b(fb.w);
      afr[qt][kh] = a;
    }
  }
  // --- staging helper (async): chunk c of this shard into buffer buf ---
  #define STAGE(buf, c) do { \
    int m0s = mbase + (c) * 128; \
    _Pragma("unroll") \
    for (int i2 = 0; i2 < 4; ++i2) { \
      int slot = i2 * 256 + t; \
      int mm = slot >> 3, gs = slot & 7; \
      int gsrc = gs ^ (mm & 7); \
      gload_lds16(KBh + (size_t)(m0s + mm) * 64 + gsrc * 8, \
                  &Kc[buf][(size_t)(i2 * 256 + (t & ~63)) * 8]); \
    } \
    if (t < 32) gload_lds16(&tauh[m0s + t * 4], &tauc[buf][0]); \
  } while (0)

  STAGE(0, 0);
  __syncthreads();
  for (int c = 0; c < 32; ++c) {
    int cur = c & 1;
    if (c + 1 < 32) STAGE(cur ^ 1, c + 1);
    #pragma unroll
    for (int mi = 0; mi < 2; ++mi) {
      int mt = 2 * w + mi;
      int m = mt * 16 + lane15;
      float tau_m = tauc[cur][m];
      short8 b0 = *(const short8*)&Kc[cur][(m * 8 + (quad       ^ (m & 7))) * 8];
      short8 b1 = *(const short8*)&Kc[cur][(m * 8 + ((4 + quad) ^ (m & 7))) * 8];
      int m_g = mbase + c * 128 + m;
      #pragma unroll
      for (int qt = 0; qt < 2; ++qt) {
        f32x4 z = {0.f, 0.f, 0.f, 0.f};
        z = __builtin_amdgcn_mfma_f32_16x16x32_bf16(afr[qt][0], b0, z, 0, 0, 0);
        z = __builtin_amdgcn_mfma_f32_16x16x32_bf16(afr[qt][1], b1, z, 0, 0, 0);
        #pragma unroll
        for (int r4 = 0; r4 < 4; ++r4) {
          if (z[r4] > tau_m) {                       // raw dot vs TAU*||K_m||
            int qloc = qt * 16 + quad * 4 + r4;      // block-local query (0..31)
            u32 p = atomicAdd(&lcnt[qloc], 1u);      // fast LDS atomic
            if (p < LSLOT) {
              lidx[qloc][p] = (u16)m_g;
            } else {                                 // rare overflow: direct global
              int ql = qq0 + qloc;
              u32 gp = atomicAdd(&pcnt[ql], 1u);
              if (gp < CAP) pidx[(size_t)ql * CAP + gp] = (u16)m_g;
            }
          }
        }
      }
    }
    __syncthreads();
  }
  #undef STAGE
  // --- flush: reserve span per query (1 global atomic each), coalesced copy-out ---
  if (t < 32) {
    u32 cnt = min(lcnt[t], (u32)LSLOT);
    gbase[t] = atomicAdd(&pcnt[qq0 + t], cnt);
  }
  __syncthreads();
  for (int q = 0; q < 32; ++q) {
    u32 cnt = min(lcnt[q], (u32)LSLOT);
    u32 gb = gbase[q];
    for (u32 s = t; s < cnt; s += 256) {
      u32 p = gb + s;
      if (p < CAP) pidx[(size_t)(qq0 + q) * CAP + p] = lidx[q][s];
    }
  }
}

// ---------- KNN select v4: 8-lane coalesced fp64 rescore (3-shfl butterfly) ----------
// -> HALF-WAVE u64-key top-33 (lanes 0-31: qA, 32-63: qB; 5 shfl steps, 1 query each)
// -> soft-blend -> fp64 V-sum.  No __syncthreads (wave-local LDS rows).
__global__ __launch_bounds__(256) void knnB_kernel(
    const u32* __restrict__ pcnt, const u16* __restrict__ pidx,
    const double* __restrict__ QM64, const float* __restrict__ Km,
    const float* __restrict__ Vm, const double* __restrict__ kinv64,
    float* __restrict__ wt)
{
  __shared__ float pool_v[QB2][CAP];
  __shared__ u16   pool_i[QB2][CAP];
  __shared__ float out_v[QB2][34];
  __shared__ u16   out_i[QB2][34];
  int t = threadIdx.x;
  int bid = blockIdx.x;
  int h2  = bid & 7;
  int qq0 = (h2 << 11) | ((bid >> 3) << 3);
  int w = t >> 6, l = t & 63;
  int qA = 2 * w, qB = 2 * w + 1;                 // this wave's two queries (block-local)
  int gA = qq0 + qA, gB = qq0 + qB;
  int n0 = min((int)pcnt[gA], CAP);               // broadcast loads, wave-uniform
  int n1 = min((int)pcnt[gB], CAP);
  int c8 = l & 7, grp8 = l >> 3;                  // 8-lane groups, 8 slots/pass
  const float*  Kmh   = Km + (size_t)h2 * 524288;
  const double* kinvh = kinv64 + h2 * 8192;
  // --- rescore query A: 24 passes x 8 slots; per-group reads 2x128B contiguous ---
  {
    double2 q0 = *(const double2*)&QM64[gA * 64 + c8 * 4];
    double2 q1 = *(const double2*)&QM64[gA * 64 + c8 * 4 + 2];
    double2 q2 = *(const double2*)&QM64[gA * 64 + 32 + c8 * 4];
    double2 q3 = *(const double2*)&QM64[gA * 64 + 32 + c8 * 4 + 2];
    #pragma unroll 8
    for (int p = 0; p < 24; ++p) {
      int j = p * 8 + grp8;
      bool val = j < n0;
      int id = val ? (int)pidx[(size_t)gA * CAP + j] : 0;
      float4 k0 = *(const float4*)&Kmh[id * 64 + c8 * 4];
      float4 k1 = *(const float4*)&Kmh[id * 64 + 32 + c8 * 4];
      double pl = q0.x * (double)k0.x;
      pl = fma(q0.y, (double)k0.y, pl);
      pl = fma(q1.x, (double)k0.z, pl);
      pl = fma(q1.y, (double)k0.w, pl);
      pl = fma(q2.x, (double)k1.x, pl);
      pl = fma(q2.y, (double)k1.y, pl);
      pl = fma(q3.x, (double)k1.z, pl);
      pl = fma(q3.y, (double)k1.w, pl);
      pl += __shfl_xor(pl, 1);
      pl += __shfl_xor(pl, 2);
      pl += __shfl_xor(pl, 4);
      if (c8 == 0) {
        pool_v[qA][j] = val ? (float)(pl * kinvh[id]) : -1e30f;
        pool_i[qA][j] = (u16)id;
      }
    }
  }
  // --- rescore query B ---
  {
    double2 q0 = *(const double2*)&QM64[gB * 64 + c8 * 4];
    double2 q1 = *(const double2*)&QM64[gB * 64 + c8 * 4 + 2];
    double2 q2 = *(const double2*)&QM64[gB * 64 + 32 + c8 * 4];
    double2 q3 = *(const double2*)&QM64[gB * 64 + 32 + c8 * 4 + 2];
    #pragma unroll 8
    for (int p = 0; p < 24; ++p) {
      int j = p * 8 + grp8;
      bool val = j < n1;
      int id = val ? (int)pidx[(size_t)gB * CAP + j] : 0;
      float4 k0 = *(const float4*)&Kmh[id * 64 + c8 * 4];
      float4 k1 = *(const float4*)&Kmh[id * 64 + 32 + c8 * 4];
      double pl = q0.x * (double)k0.x;
      pl = fma(q0.y, (double)k0.y, pl);
      pl = fma(q1.x, (double)k0.z, pl);
      pl = fma(q1.y, (double)k0.w, pl);
      pl = fma(q2.x, (double)k1.x, pl);
      pl = fma(q2.y, (double)k1.y, pl);
      pl = fma(q3.x, (double)k1.z, pl);
      pl = fma(q3.y, (double)k1.w, pl);
      pl += __shfl_xor(pl, 1);
      pl += __shfl_xor(pl, 2);
      pl += __shfl_xor(pl, 4);
      if (c8 == 0) {
        pool_v[qB][j] = val ? (float)(pl * kinvh[id]) : -1e30f;
        pool_i[qB][j] = (u16)id;
      }
    }
  }
  // no barrier: pool rows 2w,2w+1 written and read by this wave only (same-wave DS ordering)
  // --- half-wave selection: lanes 0-31 own qA, lanes 32-63 own qB; 6 keys/lane ---
  int half = l >> 5, hl = l & 31;
  int qS = 2 * w + half;                          // block-local query for this half
  u64 k0 = packkey(pool_v[qS][hl],       (int)pool_i[qS][hl]);
  u64 k1 = packkey(pool_v[qS][hl + 32],  (int)pool_i[qS][hl + 32]);
  u64 k2 = packkey(pool_v[qS][hl + 64],  (int)pool_i[qS][hl + 64]);
  u64 k3 = packkey(pool_v[qS][hl + 96],  (int)pool_i[qS][hl + 96]);
  u64 k4 = packkey(pool_v[qS][hl + 128], (int)pool_i[qS][hl + 128]);
  u64 k5 = packkey(pool_v[qS][hl + 160], (int)pool_i[qS][hl + 160]);
  for (int r = 0; r < 33; ++r) {
    u64 b = k0; int bs = 0;
    if (k1 > b) { b = k1; bs = 1; }
    if (k2 > b) { b = k2; bs = 2; }
    if (k3 > b) { b = k3; bs = 3; }
    if (k4 > b) { b = k4; bs = 4; }
    if (k5 > b) { b = k5; bs = 5; }
    u64 rk = b;
    #pragma unroll
    for (int m = 16; m >= 1; m >>= 1) {           // masks <=16 never cross halves
      u64 o = __shfl_xor(rk, m);
      if (o > rk) rk = o;
    }
    if (b == rk) {                                 // unique keys -> one lane clears
      if (bs == 0) k0 = 0ULL; else if (bs == 1) k1 = 0ULL; else if (bs == 2) k2 = 0ULL;
      else if (bs == 3) k3 = 0ULL; else if (bs == 4) k4 = 0ULL; else k5 = 0ULL;
    }
    if (hl == 0) {
      out_v[qS][r] = unpack_v(rk); out_i[qS][r] = (u16)unpack_i(rk);
    }
  }
  if (hl == 0) {   // soft-blend rank 32/33 boundary (lane 0 -> qA, lane 32 -> qB)
    float gx = out_v[qS][31] - out_v[qS][32];
    float lam = 0.5f * erfcf(gx * 471404.52f);    // 1/(sqrt(2)*1.5e-6)
    out_v[qS][31] *= (1.0f - lam);
    out_v[qS][32] *= lam;
  }
  // fp64 V-sum, both queries interleaved; deep unroll so gather loads issue ahead
  const float* Vmh = Vm + (size_t)h2 * 524288;
  double accA = 0.0, accB = 0.0;
  #pragma unroll 11
  for (int j = 0; j < 33; ++j) {
    float vA = out_v[qA][j]; int idA = out_i[qA][j];
    float vB = out_v[qB][j]; int idB = out_i[qB][j];
    if (vA > -1e29f) accA = fma((double)vA, (double)Vmh[idA * 64 + l], accA);
    if (vB > -1e29f) accB = fma((double)vB, (double)Vmh[idB * 64 + l], accB);
  }
  wt[gA * 64 + l] = (float)accA;
  wt[gB * 64 + l] = (float)accB;
}

extern "C" void kernel_launch(void* const* d_in, const int* in_sizes, int n_in,
                              void* d_out, int out_size, void* d_ws, size_t ws_size,
                              hipStream_t stream) {
  const float* x    = (const float*)d_in[0];
  const float* Wq   = (const float*)d_in[1];
  const float* bq   = (const float*)d_in[2];
  const float* Wk   = (const float*)d_in[3];
  const float* bk   = (const float*)d_in[4];
  const float* Wv   = (const float*)d_in[5];
  const float* bv   = (const float*)d_in[6];
  const float* Wo   = (const float*)d_in[7];
  const float* bo   = (const float*)d_in[8];
  const float* Km   = (const float*)d_in[9];
  const float* Vm   = (const float*)d_in[10];
  const float* gate = (const float*)d_in[11];
  float* out = (float*)d_out;
  float* ws = (float*)d_ws;
  // layout (floats). KB16 overlays WT region before knnB writes it; pool overlays Q/K.
  float*  Q      = ws;                         // [0, 1048576)
  float*  K      = ws + 1048576;               // [1048576, 2097152)
  float*  V      = ws + 2097152;               // [2097152, 3145728)
  float*  ATT    = ws + 3145728;               // [3145728, 4194304)
  float*  WT     = ws + 4194304;               // [4194304, 5242880)  (written by knnB)
  u16*    KB16   = (u16*)(ws + 4194304);       // 8.39 MB, lifetime kprep..knnA (before WT write)
  float*  QM32   = ws + 6291456;               // 1048576
  float*  TAU32  = ws + 7340032;               // 65536
  double* QM64   = (double*)(ws + 7405568);    // 1048576 doubles
  double* KINV64 = (double*)(ws + 9502720);    // 65536 doubles
  u32*    PCNT   = (u32*)ws;                   // 16384 u32, lifetime post-attn (over Q)
  u16*    PIDX   = (u16*)(ws + 16384);         // 16384*CAP u16 (over Q/K)
  gemm_qkv<<<dim3(8, 32, 3), 256, 0, stream>>>(x, Wq, bq, Wk, bk, Wv, bv, Q, K, V);
  qmem64_kernel<<<dim3(512), 256, 0, stream>>>(x, Wq, bq, QM64, QM32);
  kprep_kernel<<<dim3(256), 256, 0, stream>>>(Km, KINV64, TAU32, (u32*)KB16);
  attn_kernel<<<dim3(128, 16), 512, 0, stream>>>(Q, K, V, ATT);
  hipMemsetAsync(PCNT, 0, 16384 * sizeof(u32), stream);
  knnA_kernel<<<dim3(512, 2), 256, 0, stream>>>(QM32, KB16, TAU32, PCNT, PIDX);
  knnB_kernel<<<dim3(2048), 256, 0, stream>>>(PCNT, PIDX, QM64, Km, Vm, KINV64, WT);
  gemm_out_k<<<dim3(8, 32), 256, 0, stream>>>(ATT, WT, gate, Wo, bo, out);
}